// Round 2
// baseline (349.380 us; speedup 1.0000x reference)
//
#include <hip/hip_runtime.h>
#include <math.h>

// ---------------------------------------------------------------------------
// TemporalGCN: 2-layer LSTM (per-node sequences) -> 2 GCN rounds -> edge MLP.
//
// Algebraic restructuring vs reference:
//  * messages = einsum(adj, edge_last@epW.T) collapsed to a 6-value reduction
//    over j (wsum/asum), computed ONCE, reused by both GCN rounds.
//  * MLP layer 1 over concat(h_i,h_j,e) split into per-node u=W1a.h+b1,
//    v=W1b.h precomputes + a 5-MAC edge term.
//  * LSTM layer-1 input projection (y0 @ Wih1.T) hoisted out of the
//    recurrence into a batched GEMM (K=64 clean, scalar-pipe weights).
//
// R1 fix: k_xproj1 static LDS was 83.2 KB (> the 64 KB static __shared__
// limit -> compile failure). Output transpose now runs in TWO passes through
// a 2-tile osh buffer; total LDS 49.9 KB.
// ---------------------------------------------------------------------------

#define Hd   64
#define Ed   5
#define Fd   6
#define Bd   8
#define Wd   12
#define Nd   200
#define NSEQ (Bd*Nd)        // 1600 sequences (b,n)
#define NG   (4*Hd)         // 256 gate rows
#define NEDGE (Bd*Nd*Nd)    // 320000 edges
#define LNEPS 1e-5f

__device__ __forceinline__ float sigm(float x) { return 1.0f / (1.0f + __expf(-x)); }
__device__ __forceinline__ float tanh_fast(float x) {
  float ax = fabsf(x);
  float t  = __expf(-2.0f * ax);
  float r  = (1.0f - t) / (1.0f + t);
  return copysignf(r, x);
}

// --------------------------------------------------------------------------
// Transpose Wih1 (256x64) -> Wt1 (64x256) so xproj1 can do contiguous
// scalar loads of a k-row.
__global__ __launch_bounds__(256) void k_prep(const float* __restrict__ Wih1,
                                              float* __restrict__ Wt1) {
  int k = blockIdx.x;          // 0..63
  int j = threadIdx.x;         // 0..255
  Wt1[k * NG + j] = Wih1[j * Hd + k];
}

// --------------------------------------------------------------------------
// LSTM layer 0. 200 blocks x 256 threads; block owns 8 sequences.
// Thread j = gate row j (Whh0 row held in 64 VGPRs). x-proj (K=6) folded in.
// h broadcast via LDS float4 reads. Phase B combines gates cross-wave.
__global__ __launch_bounds__(256) void k_lstm0(
    const float* __restrict__ nf,                       // (B,W,N,F)
    const float* __restrict__ Wih0, const float* __restrict__ Whh0,
    const float* __restrict__ bih0, const float* __restrict__ bhh0,
    float* __restrict__ y0)                             // (NSEQ, W, H)
{
  __shared__ float x_sh[8 * Wd * Fd];   // 576
  __shared__ float h_sh[8 * Hd];        // 512
  __shared__ float gate_sh[8 * NG];     // 2048 (post-activation gates)

  const int tid  = threadIdx.x;
  const int seq0 = blockIdx.x * 8;

  for (int idx = tid; idx < 8 * Wd * Fd; idx += 256) {
    int s = idx / (Wd * Fd); int rem = idx % (Wd * Fd);
    int t = rem / Fd;        int f   = rem % Fd;
    int seq = seq0 + s; int b = seq / Nd; int n = seq % Nd;
    x_sh[idx] = nf[((b * Wd + t) * Nd + n) * Fd + f];
  }
  for (int idx = tid; idx < 8 * Hd; idx += 256) h_sh[idx] = 0.f;

  const int j = tid;
  float4 wh[16];
  const float4* wrow = (const float4*)(Whh0 + j * Hd);
  #pragma unroll
  for (int q = 0; q < 16; ++q) wh[q] = wrow[q];
  float wx[Fd];
  #pragma unroll
  for (int f = 0; f < Fd; ++f) wx[f] = Wih0[j * Fd + f];
  const float bias = bih0[j] + bhh0[j];
  const int jt = j >> 6;                 // 0=i,1=f,2=g,3=o (wave-uniform)

  float c0 = 0.f, c1 = 0.f;              // cell state for combine pairs
  __syncthreads();

  for (int t = 0; t < Wd; ++t) {
    // Phase A: 256 gate pre-activations x 8 seqs, activation applied here.
    for (int s = 0; s < 8; ++s) {
      const float* xp = x_sh + (s * Wd + t) * Fd;
      float a0 = bias, a1 = 0.f, a2 = 0.f, a3 = 0.f;
      #pragma unroll
      for (int f = 0; f < Fd; ++f) a1 += xp[f] * wx[f];
      const float4* h4 = (const float4*)(h_sh + s * Hd);
      #pragma unroll
      for (int q = 0; q < 16; ++q) {
        float4 hv = h4[q];
        float d = hv.x * wh[q].x + hv.y * wh[q].y + hv.z * wh[q].z + hv.w * wh[q].w;
        if ((q & 3) == 0) a0 += d; else if ((q & 3) == 1) a1 += d;
        else if ((q & 3) == 2) a2 += d; else a3 += d;
      }
      float acc = (a0 + a1) + (a2 + a3);
      gate_sh[s * NG + j] = (jt == 2) ? tanh_fast(acc) : sigm(acc);
    }
    __syncthreads();
    // Phase B: c/h update for 512 (s,u) pairs; thread owns pairs tid, tid+256.
    #pragma unroll
    for (int p = 0; p < 2; ++p) {
      int pp = tid + p * 256;
      int s = pp >> 6, u = pp & 63;
      float iv = gate_sh[s * NG + u];
      float fv = gate_sh[s * NG + 64 + u];
      float gv = gate_sh[s * NG + 128 + u];
      float ov = gate_sh[s * NG + 192 + u];
      float c = (p == 0) ? c0 : c1;
      c = fv * c + iv * gv;
      float h = ov * tanh_fast(c);
      if (p == 0) c0 = c; else c1 = c;
      h_sh[s * Hd + u] = h;
      y0[(seq0 + s) * (Wd * Hd) + t * Hd + u] = h;
    }
    __syncthreads();
  }
}

// --------------------------------------------------------------------------
// G1 = y0 @ Wih1.T + (bih1+bhh1): (19200 x 64) @ (64 x 256).
// 300 blocks x 256 thr; lane = row, wave = 64-col slab (wave-uniform cols ->
// weights via SCALAR loads; VALU-bound). Output transposed through a 2-tile
// osh in two passes (LDS total 49.9 KB < 64 KB static limit).
__global__ __launch_bounds__(256) void k_xproj1(
    const float* __restrict__ y0,    // rows = seq*12+t
    const float* __restrict__ Wt1,   // (64,256) transposed Wih1
    const float* __restrict__ bih1, const float* __restrict__ bhh1,
    float* __restrict__ G1)          // (19200, 256)
{
  __shared__ float ysh[64 * 65];        // [r][k] pad-65: conflict-free
  __shared__ float osh[2 * 64 * 65];    // two 64x64 out tiles, pad-65

  const int tid  = threadIdx.x;
  const int row0 = blockIdx.x * 64;
  for (int idx = tid; idx < 64 * 64; idx += 256) {
    int r = idx >> 6, k = idx & 63;
    ysh[r * 65 + k] = y0[(row0 + r) * Hd + k];
  }
  __syncthreads();

  const int w = __builtin_amdgcn_readfirstlane(tid >> 6);  // force uniform
  const int r = tid & 63;
  float acc[64];
  #pragma unroll
  for (int c = 0; c < 64; ++c) acc[c] = 0.f;

  const float* wbase = Wt1 + (w << 6);
  #pragma unroll 2
  for (int k = 0; k < 64; ++k) {
    float yv = ysh[r * 65 + k];
    const float* wk = wbase + k * NG;    // uniform address -> s_load
    #pragma unroll
    for (int c = 0; c < 64; ++c) acc[c] = fmaf(yv, wk[c], acc[c]);
  }
  #pragma unroll
  for (int c = 0; c < 64; ++c) acc[c] += bih1[(w << 6) + c] + bhh1[(w << 6) + c];

  // Two passes: waves {0,1} then {2,3} dump 64x64 tiles; everyone stores.
  #pragma unroll
  for (int p = 0; p < 2; ++p) {
    __syncthreads();
    if ((w >> 1) == p) {
      float* orow = osh + ((w & 1) * 64 + r) * 65;
      #pragma unroll
      for (int c = 0; c < 64; ++c) orow[c] = acc[c];  // stride-65: no conflict
    }
    __syncthreads();
    for (int idx = tid; idx < 2 * 64 * 64; idx += 256) {
      int c  = idx & 127;              // col within this 128-col slab
      int rr = idx >> 7;               // row 0..63
      G1[(row0 + rr) * NG + p * 128 + c] =
          osh[((c >> 6) * 64 + rr) * 65 + (c & 63)];   // lanes stride-1: free
    }
  }
}

// --------------------------------------------------------------------------
// LSTM layer 1 recurrence (K=64; input proj precomputed in G1). Writes only
// the final h (t=11) -> h0 (NSEQ x H).
__global__ __launch_bounds__(256) void k_lstm1(
    const float* __restrict__ G1,
    const float* __restrict__ Whh1,
    float* __restrict__ hout)        // (NSEQ, H)
{
  __shared__ float h_sh[8 * Hd];
  __shared__ float gate_sh[8 * NG];

  const int tid  = threadIdx.x;
  const int seq0 = blockIdx.x * 8;
  for (int idx = tid; idx < 8 * Hd; idx += 256) h_sh[idx] = 0.f;

  const int j = tid;
  float4 wh[16];
  const float4* wrow = (const float4*)(Whh1 + j * Hd);
  #pragma unroll
  for (int q = 0; q < 16; ++q) wh[q] = wrow[q];
  const int jt = j >> 6;
  float c0 = 0.f, c1 = 0.f;
  __syncthreads();

  for (int t = 0; t < Wd; ++t) {
    for (int s = 0; s < 8; ++s) {
      float a0 = G1[((seq0 + s) * Wd + t) * NG + j];  // bias folded in G1
      float a1 = 0.f, a2 = 0.f, a3 = 0.f;
      const float4* h4 = (const float4*)(h_sh + s * Hd);
      #pragma unroll
      for (int q = 0; q < 16; ++q) {
        float4 hv = h4[q];
        float d = hv.x * wh[q].x + hv.y * wh[q].y + hv.z * wh[q].z + hv.w * wh[q].w;
        if ((q & 3) == 0) a0 += d; else if ((q & 3) == 1) a1 += d;
        else if ((q & 3) == 2) a2 += d; else a3 += d;
      }
      float acc = (a0 + a1) + (a2 + a3);
      gate_sh[s * NG + j] = (jt == 2) ? tanh_fast(acc) : sigm(acc);
    }
    __syncthreads();
    #pragma unroll
    for (int p = 0; p < 2; ++p) {
      int pp = tid + p * 256;
      int s = pp >> 6, u = pp & 63;
      float iv = gate_sh[s * NG + u];
      float fv = gate_sh[s * NG + 64 + u];
      float gv = gate_sh[s * NG + 128 + u];
      float ov = gate_sh[s * NG + 192 + u];
      float c = (p == 0) ? c0 : c1;
      c = fv * c + iv * gv;
      float h = ov * tanh_fast(c);
      if (p == 0) c0 = c; else c1 = c;
      h_sh[s * Hd + u] = h;
      if (t == Wd - 1) hout[(seq0 + s) * Hd + u] = h;
    }
    __syncthreads();
  }
}

// --------------------------------------------------------------------------
// wsum[b,i,e] = sum_j adj[b,i,j]*edge_last[b,i,j,e]  (e<5), [5] = sum_j adj.
// Shared by both GCN rounds. 1600 blocks x 256 thr (j-parallel reduce).
__global__ __launch_bounds__(256) void k_wsum(
    const float* __restrict__ ef, const float* __restrict__ adj,
    float* __restrict__ wsum)     // (1600, 6)
{
  const int row = blockIdx.x;      // b*200+i
  const int b = row / Nd, i = row % Nd;
  const int tid = threadIdx.x;
  float p[6] = {0.f, 0.f, 0.f, 0.f, 0.f, 0.f};
  if (tid < Nd) {
    float a = adj[(b * Nd + i) * Nd + tid];
    const float* e = ef + (((b * Wd + (Wd - 1)) * Nd + i) * Nd + tid) * Ed;
    p[5] = a;
    #pragma unroll
    for (int k = 0; k < Ed; ++k) p[k] = a * e[k];
  }
  #pragma unroll
  for (int k = 0; k < 6; ++k) {
    float v = p[k];
    for (int off = 32; off > 0; off >>= 1) v += __shfl_down(v, off);
    p[k] = v;
  }
  __shared__ float red[4][6];
  if ((tid & 63) == 0) {
    #pragma unroll
    for (int k = 0; k < 6; ++k) red[tid >> 6][k] = p[k];
  }
  __syncthreads();
  if (tid < 6)
    wsum[row * 6 + tid] = red[0][tid] + red[1][tid] + red[2][tid] + red[3][tid];
}

// --------------------------------------------------------------------------
// One GCN round: hout = relu(LN(hin@gcnW.T + gcnB + messages)). 4 rows/block.
__global__ __launch_bounds__(256) void k_gcn(
    const float* __restrict__ hin, const float* __restrict__ wsum,
    const float* __restrict__ gcn_W, const float* __restrict__ gcn_b,
    const float* __restrict__ ep_W,  const float* __restrict__ ep_b,
    const float* __restrict__ ln_g,  const float* __restrict__ ln_b,
    int round, float* __restrict__ hout)
{
  const int row = blockIdx.x * 4 + (threadIdx.x >> 6);
  const int u   = threadIdx.x & 63;
  const float* gw = gcn_W + (round * Hd + u) * Hd;
  const float* ew = ep_W  + (round * Hd + u) * Ed;
  const float* hr = hin + row * Hd;
  const float* wsr = wsum + row * 6;

  float acc = gcn_b[round * Hd + u] + wsr[5] * ep_b[round * Hd + u];
  #pragma unroll
  for (int e = 0; e < Ed; ++e) acc += wsr[e] * ew[e];
  #pragma unroll 8
  for (int k = 0; k < Hd; ++k) acc += hr[k] * gw[k];

  float mu = acc;
  #pragma unroll
  for (int off = 1; off < 64; off <<= 1) mu += __shfl_xor(mu, off);
  mu *= (1.f / 64.f);
  float d = acc - mu;
  float var = d * d;
  #pragma unroll
  for (int off = 1; off < 64; off <<= 1) var += __shfl_xor(var, off);
  var *= (1.f / 64.f);
  float v = d * rsqrtf(var + LNEPS) * ln_g[round * Hd + u] + ln_b[round * Hd + u];
  hout[row * Hd + u] = fmaxf(v, 0.f);
}

// --------------------------------------------------------------------------
// u = W1a.h + b1 (row-major), v = W1b.h (TRANSPOSED [n][row] so the edge MLP
// v-read is coalesced over j).
__global__ __launch_bounds__(128) void k_uv(
    const float* __restrict__ h, const float* __restrict__ W1,
    const float* __restrict__ b1,
    float* __restrict__ u, float* __restrict__ vt)
{
  const int row = blockIdx.x;
  const int tid = threadIdx.x;
  const float* hr = h + row * Hd;
  if (tid < 64) {
    const float* wr = W1 + tid * 133;          // cols 0..63 (h_i)
    float acc = b1[tid];
    #pragma unroll 8
    for (int k = 0; k < Hd; ++k) acc += hr[k] * wr[k];
    u[row * Hd + tid] = acc;
  } else {
    const int n = tid - 64;
    const float* wr = W1 + n * 133 + 64;       // cols 64..127 (h_j)
    float acc = 0.f;
    #pragma unroll 8
    for (int k = 0; k < Hd; ++k) acc += hr[k] * wr[k];
    vt[n * NSEQ + row] = acc;
  }
}

// --------------------------------------------------------------------------
// Edge MLP: thread per edge. z1[64] lives in VGPRs; W1c/W2/W3/b2 have
// wave-uniform indices -> scalar-pipe loads, fmac v,s,v at VALU issue peak.
__global__ __launch_bounds__(256) void k_mlp(
    const float* __restrict__ ef,
    const float* __restrict__ u, const float* __restrict__ vt,
    const float* __restrict__ W1,
    const float* __restrict__ W2, const float* __restrict__ b2,
    const float* __restrict__ W3, const float* __restrict__ b3,
    float* __restrict__ out)
{
  const int idx = blockIdx.x * 256 + threadIdx.x;   // < 320000
  const int b   = idx / (Nd * Nd);
  const int rem = idx - b * Nd * Nd;
  const int i   = rem / Nd;
  const int jj  = rem - i * Nd;

  const float* e = ef + (((b * Wd + (Wd - 1)) * Nd + i) * Nd + jj) * Ed;
  float e5[Ed];
  #pragma unroll
  for (int q = 0; q < Ed; ++q) e5[q] = e[q];

  const float* ur = u + (b * Nd + i) * Hd;
  const int vcol = b * Nd + jj;

  float z1[64];
  #pragma unroll
  for (int k = 0; k < 64; ++k) {
    float acc = ur[k] + vt[k * NSEQ + vcol];
    const float* w1c = W1 + k * 133 + 128;      // uniform -> scalar loads
    #pragma unroll
    for (int q = 0; q < Ed; ++q) acc += e5[q] * w1c[q];
    z1[k] = fmaxf(acc, 0.f);
  }

  float logit = b3[0];
  #pragma unroll 4
  for (int o = 0; o < 32; ++o) {
    float a0 = b2[o], a1 = 0.f, a2 = 0.f, a3 = 0.f;
    const float* w2 = W2 + o * 64;              // uniform -> scalar loads
    #pragma unroll
    for (int k = 0; k < 64; k += 4) {
      a0 += w2[k]     * z1[k];
      a1 += w2[k + 1] * z1[k + 1];
      a2 += w2[k + 2] * z1[k + 2];
      a3 += w2[k + 3] * z1[k + 3];
    }
    float z2 = fmaxf((a0 + a1) + (a2 + a3), 0.f);
    logit += W3[o] * z2;
  }
  out[idx] = 1.f / (1.f + __expf(-logit));
}

// --------------------------------------------------------------------------
extern "C" void kernel_launch(void* const* d_in, const int* in_sizes, int n_in,
                              void* d_out, int out_size, void* d_ws, size_t ws_size,
                              hipStream_t stream) {
  (void)in_sizes; (void)n_in; (void)out_size; (void)ws_size;
  const float* nf   = (const float*)d_in[0];
  const float* ef   = (const float*)d_in[1];
  const float* adj  = (const float*)d_in[2];
  const float* Wih0 = (const float*)d_in[3];
  const float* Whh0 = (const float*)d_in[4];
  const float* bih0 = (const float*)d_in[5];
  const float* bhh0 = (const float*)d_in[6];
  const float* Wih1 = (const float*)d_in[7];
  const float* Whh1 = (const float*)d_in[8];
  const float* bih1 = (const float*)d_in[9];
  const float* bhh1 = (const float*)d_in[10];
  const float* gcnW = (const float*)d_in[11];
  const float* gcnB = (const float*)d_in[12];
  const float* epW  = (const float*)d_in[13];
  const float* epB  = (const float*)d_in[14];
  const float* lnG  = (const float*)d_in[15];
  const float* lnB  = (const float*)d_in[16];
  const float* W1   = (const float*)d_in[17];
  const float* b1   = (const float*)d_in[18];
  const float* W2   = (const float*)d_in[19];
  const float* b2   = (const float*)d_in[20];
  const float* W3   = (const float*)d_in[21];
  const float* b3   = (const float*)d_in[22];
  float* out = (float*)d_out;

  // Workspace layout (floats). Total ~6.68M floats = 26.7 MB.
  float* ws  = (float*)d_ws;
  float* y0  = ws;                         // 1600*12*64 = 1,228,800
  float* G1  = y0  + 1228800;              // 19200*256  = 4,915,200
  float* Wt1 = G1  + 4915200;              // 64*256     = 16,384
  float* h0  = Wt1 + 16384;                // 1600*64    = 102,400
  float* wsm = h0  + 102400;               // 1600*6     = 9,600
  float* hA  = wsm + 9600;                 // 102,400
  float* hB  = hA  + 102400;               // 102,400
  float* uu  = hB  + 102400;               // 102,400
  float* vt  = uu  + 102400;               // 102,400

  k_prep  <<<64,   256, 0, stream>>>(Wih1, Wt1);
  k_lstm0 <<<200,  256, 0, stream>>>(nf, Wih0, Whh0, bih0, bhh0, y0);
  k_xproj1<<<300,  256, 0, stream>>>(y0, Wt1, bih1, bhh1, G1);
  k_lstm1 <<<200,  256, 0, stream>>>(G1, Whh1, h0);
  k_wsum  <<<1600, 256, 0, stream>>>(ef, adj, wsm);
  k_gcn   <<<400,  256, 0, stream>>>(h0, wsm, gcnW, gcnB, epW, epB, lnG, lnB, 0, hA);
  k_gcn   <<<400,  256, 0, stream>>>(hA, wsm, gcnW, gcnB, epW, epB, lnG, lnB, 1, hB);
  k_uv    <<<1600, 128, 0, stream>>>(hB, W1, b1, uu, vt);
  k_mlp   <<<1250, 256, 0, stream>>>(ef, uu, vt, W1, W2, b2, W3, b3, out);
}

// Round 4
// 277.213 us; speedup vs baseline: 1.2603x; 1.2603x over previous
//
#include <hip/hip_runtime.h>
#include <math.h>

// ---------------------------------------------------------------------------
// TemporalGCN: 2-layer LSTM (per-node sequences) -> 2 GCN rounds -> edge MLP.
//
// R2 profile: k_lstm0/1 at 200 blocks were latency-bound (Occupancy 8.6%,
// VALUBusy 15.9%, HBM 1.6%). Fix: 1 sequence per block -> 1600 blocks,
// identical arithmetic; G1/x prefetched one timestep ahead.
// R3 bench was an infra flake (container died on the R0 stub too); this is
// the same source resubmitted to test the R2->R3 prediction.
// ---------------------------------------------------------------------------

#define Hd   64
#define Ed   5
#define Fd   6
#define Bd   8
#define Wd   12
#define Nd   200
#define NSEQ (Bd*Nd)        // 1600 sequences (b,n)
#define NG   (4*Hd)         // 256 gate rows
#define NEDGE (Bd*Nd*Nd)    // 320000 edges
#define LNEPS 1e-5f

__device__ __forceinline__ float sigm(float x) { return 1.0f / (1.0f + __expf(-x)); }
__device__ __forceinline__ float tanh_fast(float x) {
  float ax = fabsf(x);
  float t  = __expf(-2.0f * ax);
  float r  = (1.0f - t) / (1.0f + t);
  return copysignf(r, x);
}

// --------------------------------------------------------------------------
// Transpose Wih1 (256x64) -> Wt1 (64x256) so xproj1 can do contiguous
// scalar loads of a k-row.
__global__ __launch_bounds__(256) void k_prep(const float* __restrict__ Wih1,
                                              float* __restrict__ Wt1) {
  int k = blockIdx.x;          // 0..63
  int j = threadIdx.x;         // 0..255
  Wt1[k * NG + j] = Wih1[j * Hd + k];
}

// --------------------------------------------------------------------------
// LSTM layer 0. 1600 blocks x 256 threads; block owns ONE sequence.
// Thread j = gate row j (Whh0 row held in 64 VGPRs). x-proj (K=6) folded in.
// h broadcast via LDS float4 reads (all-lane same address = free broadcast).
__global__ __launch_bounds__(256) void k_lstm0(
    const float* __restrict__ nf,                       // (B,W,N,F)
    const float* __restrict__ Wih0, const float* __restrict__ Whh0,
    const float* __restrict__ bih0, const float* __restrict__ bhh0,
    float* __restrict__ y0)                             // (NSEQ, W, H)
{
  __shared__ float x_sh[Wd * Fd];   // 72
  __shared__ float h_sh[Hd];        // 64
  __shared__ float gate_sh[NG];     // 256 (post-activation gates)

  const int tid = threadIdx.x;
  const int seq = blockIdx.x;
  const int b = seq / Nd, n = seq % Nd;

  if (tid < Wd * Fd) {
    int t = tid / Fd, f = tid % Fd;
    x_sh[tid] = nf[((b * Wd + t) * Nd + n) * Fd + f];
  }
  if (tid < Hd) h_sh[tid] = 0.f;

  const int j = tid;
  float4 wh[16];
  const float4* wrow = (const float4*)(Whh0 + j * Hd);
  #pragma unroll
  for (int q = 0; q < 16; ++q) wh[q] = wrow[q];
  float wx[Fd];
  #pragma unroll
  for (int f = 0; f < Fd; ++f) wx[f] = Wih0[j * Fd + f];
  const float bias = bih0[j] + bhh0[j];
  const int jt = j >> 6;                 // 0=i,1=f,2=g,3=o (wave-uniform)

  float c = 0.f;                         // cell state (valid for tid<64)
  __syncthreads();

  for (int t = 0; t < Wd; ++t) {
    // Phase A: 256 gate pre-activations, activation applied here.
    const float* xp = x_sh + t * Fd;
    float a0 = bias, a1 = 0.f, a2 = 0.f, a3 = 0.f;
    #pragma unroll
    for (int f = 0; f < Fd; ++f) a1 += xp[f] * wx[f];
    const float4* h4 = (const float4*)h_sh;
    #pragma unroll
    for (int q = 0; q < 16; ++q) {
      float4 hv = h4[q];
      float d = hv.x * wh[q].x + hv.y * wh[q].y + hv.z * wh[q].z + hv.w * wh[q].w;
      if ((q & 3) == 0) a0 += d; else if ((q & 3) == 1) a1 += d;
      else if ((q & 3) == 2) a2 += d; else a3 += d;
    }
    float acc = (a0 + a1) + (a2 + a3);
    gate_sh[j] = (jt == 2) ? tanh_fast(acc) : sigm(acc);
    __syncthreads();
    // Phase B: c/h update, threads 0..63 (unit u = tid).
    if (tid < Hd) {
      float iv = gate_sh[tid];
      float fv = gate_sh[64 + tid];
      float gv = gate_sh[128 + tid];
      float ov = gate_sh[192 + tid];
      c = fv * c + iv * gv;
      float h = ov * tanh_fast(c);
      h_sh[tid] = h;
      y0[seq * (Wd * Hd) + t * Hd + tid] = h;
    }
    __syncthreads();
  }
}

// --------------------------------------------------------------------------
// G1 = y0 @ Wih1.T + (bih1+bhh1): (19200 x 64) @ (64 x 256).
// 300 blocks x 256 thr; lane = row, wave = 64-col slab (wave-uniform cols ->
// weights via SCALAR loads; VALU-bound). Output transposed through a 2-tile
// osh in two passes (LDS total 49.9 KB < 64 KB static limit).
__global__ __launch_bounds__(256) void k_xproj1(
    const float* __restrict__ y0,    // rows = seq*12+t
    const float* __restrict__ Wt1,   // (64,256) transposed Wih1
    const float* __restrict__ bih1, const float* __restrict__ bhh1,
    float* __restrict__ G1)          // (19200, 256)
{
  __shared__ float ysh[64 * 65];        // [r][k] pad-65: conflict-free
  __shared__ float osh[2 * 64 * 65];    // two 64x64 out tiles, pad-65

  const int tid  = threadIdx.x;
  const int row0 = blockIdx.x * 64;
  for (int idx = tid; idx < 64 * 64; idx += 256) {
    int r = idx >> 6, k = idx & 63;
    ysh[r * 65 + k] = y0[(row0 + r) * Hd + k];
  }
  __syncthreads();

  const int w = __builtin_amdgcn_readfirstlane(tid >> 6);  // force uniform
  const int r = tid & 63;
  float acc[64];
  #pragma unroll
  for (int c = 0; c < 64; ++c) acc[c] = 0.f;

  const float* wbase = Wt1 + (w << 6);
  #pragma unroll 2
  for (int k = 0; k < 64; ++k) {
    float yv = ysh[r * 65 + k];
    const float* wk = wbase + k * NG;    // uniform address -> s_load
    #pragma unroll
    for (int c = 0; c < 64; ++c) acc[c] = fmaf(yv, wk[c], acc[c]);
  }
  #pragma unroll
  for (int c = 0; c < 64; ++c) acc[c] += bih1[(w << 6) + c] + bhh1[(w << 6) + c];

  // Two passes: waves {0,1} then {2,3} dump 64x64 tiles; everyone stores.
  #pragma unroll
  for (int p = 0; p < 2; ++p) {
    __syncthreads();
    if ((w >> 1) == p) {
      float* orow = osh + ((w & 1) * 64 + r) * 65;
      #pragma unroll
      for (int c = 0; c < 64; ++c) orow[c] = acc[c];  // stride-65: no conflict
    }
    __syncthreads();
    for (int idx = tid; idx < 2 * 64 * 64; idx += 256) {
      int c  = idx & 127;              // col within this 128-col slab
      int rr = idx >> 7;               // row 0..63
      G1[(row0 + rr) * NG + p * 128 + c] =
          osh[((c >> 6) * 64 + rr) * 65 + (c & 63)];   // lanes stride-1: free
    }
  }
}

// --------------------------------------------------------------------------
// LSTM layer 1 recurrence (K=64; input proj precomputed in G1). 1600 blocks,
// ONE sequence per block. G1 prefetched one timestep ahead (coalesced:
// thread j reads G1[row*256+j]). Writes only final h (t=11) -> h0.
__global__ __launch_bounds__(256) void k_lstm1(
    const float* __restrict__ G1,
    const float* __restrict__ Whh1,
    float* __restrict__ hout)        // (NSEQ, H)
{
  __shared__ float h_sh[Hd];
  __shared__ float gate_sh[NG];

  const int tid = threadIdx.x;
  const int seq = blockIdx.x;
  if (tid < Hd) h_sh[tid] = 0.f;

  const int j = tid;
  float4 wh[16];
  const float4* wrow = (const float4*)(Whh1 + j * Hd);
  #pragma unroll
  for (int q = 0; q < 16; ++q) wh[q] = wrow[q];
  const int jt = j >> 6;
  float c = 0.f;

  float g_cur = G1[(seq * Wd + 0) * NG + j];   // prefetch t=0
  __syncthreads();

  for (int t = 0; t < Wd; ++t) {
    float g_next = (t + 1 < Wd) ? G1[(seq * Wd + t + 1) * NG + j] : 0.f;
    float a0 = g_cur;                          // bias folded in G1
    float a1 = 0.f, a2 = 0.f, a3 = 0.f;
    const float4* h4 = (const float4*)h_sh;
    #pragma unroll
    for (int q = 0; q < 16; ++q) {
      float4 hv = h4[q];
      float d = hv.x * wh[q].x + hv.y * wh[q].y + hv.z * wh[q].z + hv.w * wh[q].w;
      if ((q & 3) == 0) a0 += d; else if ((q & 3) == 1) a1 += d;
      else if ((q & 3) == 2) a2 += d; else a3 += d;
    }
    float acc = (a0 + a1) + (a2 + a3);
    gate_sh[j] = (jt == 2) ? tanh_fast(acc) : sigm(acc);
    __syncthreads();
    if (tid < Hd) {
      float iv = gate_sh[tid];
      float fv = gate_sh[64 + tid];
      float gv = gate_sh[128 + tid];
      float ov = gate_sh[192 + tid];
      c = fv * c + iv * gv;
      float h = ov * tanh_fast(c);
      h_sh[tid] = h;
      if (t == Wd - 1) hout[seq * Hd + tid] = h;
    }
    __syncthreads();
    g_cur = g_next;
  }
}

// --------------------------------------------------------------------------
// wsum[b,i,e] = sum_j adj[b,i,j]*edge_last[b,i,j,e]  (e<5), [5] = sum_j adj.
// Shared by both GCN rounds. 1600 blocks x 256 thr (j-parallel reduce).
__global__ __launch_bounds__(256) void k_wsum(
    const float* __restrict__ ef, const float* __restrict__ adj,
    float* __restrict__ wsum)     // (1600, 6)
{
  const int row = blockIdx.x;      // b*200+i
  const int b = row / Nd, i = row % Nd;
  const int tid = threadIdx.x;
  float p[6] = {0.f, 0.f, 0.f, 0.f, 0.f, 0.f};
  if (tid < Nd) {
    float a = adj[(b * Nd + i) * Nd + tid];
    const float* e = ef + (((b * Wd + (Wd - 1)) * Nd + i) * Nd + tid) * Ed;
    p[5] = a;
    #pragma unroll
    for (int k = 0; k < Ed; ++k) p[k] = a * e[k];
  }
  #pragma unroll
  for (int k = 0; k < 6; ++k) {
    float v = p[k];
    for (int off = 32; off > 0; off >>= 1) v += __shfl_down(v, off);
    p[k] = v;
  }
  __shared__ float red[4][6];
  if ((tid & 63) == 0) {
    #pragma unroll
    for (int k = 0; k < 6; ++k) red[tid >> 6][k] = p[k];
  }
  __syncthreads();
  if (tid < 6)
    wsum[row * 6 + tid] = red[0][tid] + red[1][tid] + red[2][tid] + red[3][tid];
}

// --------------------------------------------------------------------------
// One GCN round: hout = relu(LN(hin@gcnW.T + gcnB + messages)). 4 rows/block.
__global__ __launch_bounds__(256) void k_gcn(
    const float* __restrict__ hin, const float* __restrict__ wsum,
    const float* __restrict__ gcn_W, const float* __restrict__ gcn_b,
    const float* __restrict__ ep_W,  const float* __restrict__ ep_b,
    const float* __restrict__ ln_g,  const float* __restrict__ ln_b,
    int round, float* __restrict__ hout)
{
  const int row = blockIdx.x * 4 + (threadIdx.x >> 6);
  const int u   = threadIdx.x & 63;
  const float* gw = gcn_W + (round * Hd + u) * Hd;
  const float* ew = ep_W  + (round * Hd + u) * Ed;
  const float* hr = hin + row * Hd;
  const float* wsr = wsum + row * 6;

  float acc = gcn_b[round * Hd + u] + wsr[5] * ep_b[round * Hd + u];
  #pragma unroll
  for (int e = 0; e < Ed; ++e) acc += wsr[e] * ew[e];
  #pragma unroll 8
  for (int k = 0; k < Hd; ++k) acc += hr[k] * gw[k];

  float mu = acc;
  #pragma unroll
  for (int off = 1; off < 64; off <<= 1) mu += __shfl_xor(mu, off);
  mu *= (1.f / 64.f);
  float d = acc - mu;
  float var = d * d;
  #pragma unroll
  for (int off = 1; off < 64; off <<= 1) var += __shfl_xor(var, off);
  var *= (1.f / 64.f);
  float v = d * rsqrtf(var + LNEPS) * ln_g[round * Hd + u] + ln_b[round * Hd + u];
  hout[row * Hd + u] = fmaxf(v, 0.f);
}

// --------------------------------------------------------------------------
// u = W1a.h + b1 (row-major), v = W1b.h (TRANSPOSED [n][row] so the edge MLP
// v-read is coalesced over j).
__global__ __launch_bounds__(128) void k_uv(
    const float* __restrict__ h, const float* __restrict__ W1,
    const float* __restrict__ b1,
    float* __restrict__ u, float* __restrict__ vt)
{
  const int row = blockIdx.x;
  const int tid = threadIdx.x;
  const float* hr = h + row * Hd;
  if (tid < 64) {
    const float* wr = W1 + tid * 133;          // cols 0..63 (h_i)
    float acc = b1[tid];
    #pragma unroll 8
    for (int k = 0; k < Hd; ++k) acc += hr[k] * wr[k];
    u[row * Hd + tid] = acc;
  } else {
    const int n = tid - 64;
    const float* wr = W1 + n * 133 + 64;       // cols 64..127 (h_j)
    float acc = 0.f;
    #pragma unroll 8
    for (int k = 0; k < Hd; ++k) acc += hr[k] * wr[k];
    vt[n * NSEQ + row] = acc;
  }
}

// --------------------------------------------------------------------------
// Edge MLP: thread per edge. z1[64] lives in VGPRs; W1c/W2/W3/b2 have
// wave-uniform indices -> scalar-pipe loads, fmac v,s,v at VALU issue peak.
__global__ __launch_bounds__(256) void k_mlp(
    const float* __restrict__ ef,
    const float* __restrict__ u, const float* __restrict__ vt,
    const float* __restrict__ W1,
    const float* __restrict__ W2, const float* __restrict__ b2,
    const float* __restrict__ W3, const float* __restrict__ b3,
    float* __restrict__ out)
{
  const int idx = blockIdx.x * 256 + threadIdx.x;   // < 320000
  const int b   = idx / (Nd * Nd);
  const int rem = idx - b * Nd * Nd;
  const int i   = rem / Nd;
  const int jj  = rem - i * Nd;

  const float* e = ef + (((b * Wd + (Wd - 1)) * Nd + i) * Nd + jj) * Ed;
  float e5[Ed];
  #pragma unroll
  for (int q = 0; q < Ed; ++q) e5[q] = e[q];

  const float* ur = u + (b * Nd + i) * Hd;
  const int vcol = b * Nd + jj;

  float z1[64];
  #pragma unroll
  for (int k = 0; k < 64; ++k) {
    float acc = ur[k] + vt[k * NSEQ + vcol];
    const float* w1c = W1 + k * 133 + 128;      // uniform -> scalar loads
    #pragma unroll
    for (int q = 0; q < Ed; ++q) acc += e5[q] * w1c[q];
    z1[k] = fmaxf(acc, 0.f);
  }

  float logit = b3[0];
  #pragma unroll 4
  for (int o = 0; o < 32; ++o) {
    float a0 = b2[o], a1 = 0.f, a2 = 0.f, a3 = 0.f;
    const float* w2 = W2 + o * 64;              // uniform -> scalar loads
    #pragma unroll
    for (int k = 0; k < 64; k += 4) {
      a0 += w2[k]     * z1[k];
      a1 += w2[k + 1] * z1[k + 1];
      a2 += w2[k + 2] * z1[k + 2];
      a3 += w2[k + 3] * z1[k + 3];
    }
    float z2 = fmaxf((a0 + a1) + (a2 + a3), 0.f);
    logit += W3[o] * z2;
  }
  out[idx] = 1.f / (1.f + __expf(-logit));
}

// --------------------------------------------------------------------------
extern "C" void kernel_launch(void* const* d_in, const int* in_sizes, int n_in,
                              void* d_out, int out_size, void* d_ws, size_t ws_size,
                              hipStream_t stream) {
  (void)in_sizes; (void)n_in; (void)out_size; (void)ws_size;
  const float* nf   = (const float*)d_in[0];
  const float* ef   = (const float*)d_in[1];
  const float* adj  = (const float*)d_in[2];
  const float* Wih0 = (const float*)d_in[3];
  const float* Whh0 = (const float*)d_in[4];
  const float* bih0 = (const float*)d_in[5];
  const float* bhh0 = (const float*)d_in[6];
  const float* Wih1 = (const float*)d_in[7];
  const float* Whh1 = (const float*)d_in[8];
  const float* bih1 = (const float*)d_in[9];
  const float* bhh1 = (const float*)d_in[10];
  const float* gcnW = (const float*)d_in[11];
  const float* gcnB = (const float*)d_in[12];
  const float* epW  = (const float*)d_in[13];
  const float* epB  = (const float*)d_in[14];
  const float* lnG  = (const float*)d_in[15];
  const float* lnB  = (const float*)d_in[16];
  const float* W1   = (const float*)d_in[17];
  const float* b1   = (const float*)d_in[18];
  const float* W2   = (const float*)d_in[19];
  const float* b2   = (const float*)d_in[20];
  const float* W3   = (const float*)d_in[21];
  const float* b3   = (const float*)d_in[22];
  float* out = (float*)d_out;

  // Workspace layout (floats). Total ~6.68M floats = 26.7 MB.
  float* ws  = (float*)d_ws;
  float* y0  = ws;                         // 1600*12*64 = 1,228,800
  float* G1  = y0  + 1228800;              // 19200*256  = 4,915,200
  float* Wt1 = G1  + 4915200;              // 64*256     = 16,384
  float* h0  = Wt1 + 16384;                // 1600*64    = 102,400
  float* wsm = h0  + 102400;               // 1600*6     = 9,600
  float* hA  = wsm + 9600;                 // 102,400
  float* hB  = hA  + 102400;               // 102,400
  float* uu  = hB  + 102400;               // 102,400
  float* vt  = uu  + 102400;               // 102,400

  k_prep  <<<64,   256, 0, stream>>>(Wih1, Wt1);
  k_lstm0 <<<NSEQ, 256, 0, stream>>>(nf, Wih0, Whh0, bih0, bhh0, y0);
  k_xproj1<<<300,  256, 0, stream>>>(y0, Wt1, bih1, bhh1, G1);
  k_lstm1 <<<NSEQ, 256, 0, stream>>>(G1, Whh1, h0);
  k_wsum  <<<1600, 256, 0, stream>>>(ef, adj, wsm);
  k_gcn   <<<400,  256, 0, stream>>>(h0, wsm, gcnW, gcnB, epW, epB, lnG, lnB, 0, hA);
  k_gcn   <<<400,  256, 0, stream>>>(hA, wsm, gcnW, gcnB, epW, epB, lnG, lnB, 1, hB);
  k_uv    <<<1600, 128, 0, stream>>>(hB, W1, b1, uu, vt);
  k_mlp   <<<1250, 256, 0, stream>>>(ef, uu, vt, W1, W2, b2, W3, b3, out);
}